// Round 10
// baseline (355.696 us; speedup 1.0000x reference)
//
#include <hip/hip_runtime.h>
#include <hip/hip_bf16.h>

#define Bc 4
#define Tc 16
#define Nc 1024
#define Ec 16384
#define FIN 128
#define Hc 256
#define FFc 1024
#define NHc 8
#define Lc 2
#define HDc 32
#define Gc 64
#define EPSc 1e-5f

typedef __bf16 v8bf __attribute__((ext_vector_type(8)));
typedef float v4f __attribute__((ext_vector_type(4)));

// ================= prep: blocks 0..63 = CSR per graph; 64..127 = W pack =================
__global__ __launch_bounds__(1024) void prep_kernel(
        const int* __restrict__ ei, const float* __restrict__ Wl, const float* __restrict__ Wr,
        float* __restrict__ invdeg, float* __restrict__ cw, int* __restrict__ off,
        unsigned short* __restrict__ elist, float* __restrict__ uv,
        __bf16* __restrict__ pH, __bf16* __restrict__ pL) {
    __shared__ int degs[Nc];
    __shared__ float inv[Nc];
    __shared__ float cl[Nc];
    __shared__ int wsum[16];
    if (blockIdx.x >= 64) {
        // pack: Wcat[256][256]=[Wl;Wr] -> MFMA B-frag order, bf16 hi+lo
        int id = (blockIdx.x - 64) * 1024 + threadIdx.x;   // 0..65535 = bidOld*512 + t
        int t = id & 511;
        int bidOld = id >> 9;
        int lane = t >> 3, j = t & 7;
        int kc = bidOld >> 4, nt = bidOld & 15;
        int k = kc * 32 + ((lane >> 4) << 3) + j;
        int n = nt * 16 + (lane & 15);
        float wv = (k < 128) ? Wl[(size_t)k * Hc + n] : Wr[(size_t)(k - 128) * Hc + n];
        __bf16 hi = (__bf16)wv;
        pH[id] = hi;
        pL[id] = (__bf16)(wv - (float)hi);
        return;
    }
    int g = blockIdx.x, t = threadIdx.x;
    const int* src = ei + (size_t)g * 2 * Ec;
    const int* dst = src + Ec;
    if (t < 512) uv[g * 512 + t] = 0.f;
    degs[t] = 0; cl[t] = 0.f;
    __syncthreads();
    for (int e = t; e < Ec; e += 1024) atomicAdd(&degs[dst[e] & (Nc - 1)], 1);
    __syncthreads();
    float iv = 1.0f / fmaxf((float)degs[t], 1.0f);
    inv[t] = iv;
    invdeg[g * Nc + t] = iv;
    __syncthreads();
    for (int e = t; e < Ec; e += 1024) atomicAdd(&cl[src[e] & (Nc - 1)], inv[dst[e] & (Nc - 1)]);
    __syncthreads();
    cw[g * Nc + t] = cl[t];
    int own = degs[t];
    int lane = t & 63, wv2 = t >> 6;
    int val = own;
#pragma unroll
    for (int ofs = 1; ofs < 64; ofs <<= 1) {
        int v = __shfl_up(val, ofs, 64);
        if (lane >= ofs) val += v;
    }
    if (lane == 63) wsum[wv2] = val;
    __syncthreads();
    if (wv2 == 0 && lane < 16) {
        int wval = wsum[lane];
#pragma unroll
        for (int ofs = 1; ofs < 16; ofs <<= 1) {
            int v = __shfl_up(wval, ofs, 64);
            if (lane >= ofs) wval += v;
        }
        wsum[lane] = wval;
    }
    __syncthreads();
    int incl = val + ((wv2 > 0) ? wsum[wv2 - 1] : 0);
    int excl = incl - own;
    off[g * 1032 + t] = excl;
    if (t == 1023) off[g * 1032 + Nc] = incl;
    degs[t] = excl;
    __syncthreads();
    for (int e = t; e < Ec; e += 1024) {
        int d = dst[e] & (Nc - 1);
        int slot = atomicAdd(&degs[d], 1);
        elist[(size_t)g * Ec + slot] = (unsigned short)(src[e] & (Nc - 1));
    }
}

// ================= SAGE v3: 64-row blocks, bf16 A pre-split in LDS, 4x B reuse =================
__global__ __launch_bounds__(512, 4) void sage_kernel(
        const float* __restrict__ x, const unsigned short* __restrict__ elist,
        const int* __restrict__ off, const float* __restrict__ invdeg,
        const float* __restrict__ cw, const __bf16* __restrict__ pH,
        const __bf16* __restrict__ pL, const float* __restrict__ bias,
        float* __restrict__ uv) {
    __shared__ __bf16 AH[64 * 264];    // [row][k 0..255], stride 264 (2-way bank alias = free)
    __shared__ __bf16 AL[64 * 264];
    int tid = threadIdx.x, bid = blockIdx.x;
    int g = bid & 63, cc = bid >> 6, r0 = cc * 64;   // XCD swizzle: graph -> one XCD
    const unsigned short* el = elist + (size_t)g * Ec;
    const float* xg = x + (size_t)g * Nc * FIN;

    // phase A: thread = (row lr 0..63, 16-float chunk ch 0..7)
    {
        int lr = tid >> 3, ch = tid & 7;
        int n = r0 + lr;
        int o0 = off[g * 1032 + n], o1 = off[g * 1032 + n + 1];
        float4 a0 = {0.f,0.f,0.f,0.f}, a1 = a0, a2 = a0, a3 = a0;
        const float* xc = xg + ch * 16;
        int e = o0;
        for (; e + 4 <= o1; e += 4) {
            int s0 = el[e], s1 = el[e+1], s2 = el[e+2], s3 = el[e+3];
            const float4* p0 = (const float4*)(xc + (size_t)s0 * FIN);
            const float4* p1 = (const float4*)(xc + (size_t)s1 * FIN);
            const float4* p2 = (const float4*)(xc + (size_t)s2 * FIN);
            const float4* p3 = (const float4*)(xc + (size_t)s3 * FIN);
            float4 v00=p0[0], v01=p0[1], v02=p0[2], v03=p0[3];
            float4 v10=p1[0], v11=p1[1], v12=p1[2], v13=p1[3];
            float4 v20=p2[0], v21=p2[1], v22=p2[2], v23=p2[3];
            float4 v30=p3[0], v31=p3[1], v32=p3[2], v33=p3[3];
            a0.x += v00.x+v10.x+v20.x+v30.x; a0.y += v00.y+v10.y+v20.y+v30.y;
            a0.z += v00.z+v10.z+v20.z+v30.z; a0.w += v00.w+v10.w+v20.w+v30.w;
            a1.x += v01.x+v11.x+v21.x+v31.x; a1.y += v01.y+v11.y+v21.y+v31.y;
            a1.z += v01.z+v11.z+v21.z+v31.z; a1.w += v01.w+v11.w+v21.w+v31.w;
            a2.x += v02.x+v12.x+v22.x+v32.x; a2.y += v02.y+v12.y+v22.y+v32.y;
            a2.z += v02.z+v12.z+v22.z+v32.z; a2.w += v02.w+v12.w+v22.w+v32.w;
            a3.x += v03.x+v13.x+v23.x+v33.x; a3.y += v03.y+v13.y+v23.y+v33.y;
            a3.z += v03.z+v13.z+v23.z+v33.z; a3.w += v03.w+v13.w+v23.w+v33.w;
        }
        for (; e < o1; ++e) {
            const float4* p = (const float4*)(xc + (size_t)el[e] * FIN);
            float4 v0=p[0], v1=p[1], v2=p[2], v3=p[3];
            a0.x+=v0.x; a0.y+=v0.y; a0.z+=v0.z; a0.w+=v0.w;
            a1.x+=v1.x; a1.y+=v1.y; a1.z+=v1.z; a1.w+=v1.w;
            a2.x+=v2.x; a2.y+=v2.y; a2.z+=v2.z; a2.w+=v2.w;
            a3.x+=v3.x; a3.y+=v3.y; a3.z+=v3.z; a3.w+=v3.w;
        }
        float iv = invdeg[g * Nc + n];
        float vals[16] = {a0.x*iv,a0.y*iv,a0.z*iv,a0.w*iv, a1.x*iv,a1.y*iv,a1.z*iv,a1.w*iv,
                          a2.x*iv,a2.y*iv,a2.z*iv,a2.w*iv, a3.x*iv,a3.y*iv,a3.z*iv,a3.w*iv};
        v8bf h0, h1v, l0, l1v;
#pragma unroll
        for (int i = 0; i < 8; ++i) {
            __bf16 hb = (__bf16)vals[i];
            h0[i] = hb; l0[i] = (__bf16)(vals[i] - (float)hb);
            __bf16 hb2 = (__bf16)vals[i+8];
            h1v[i] = hb2; l1v[i] = (__bf16)(vals[i+8] - (float)hb2);
        }
        __bf16* dh = &AH[lr * 264 + ch * 16];
        __bf16* dl = &AL[lr * 264 + ch * 16];
        *(v8bf*)dh = h0; *(v8bf*)(dh + 8) = h1v;
        *(v8bf*)dl = l0; *(v8bf*)(dl + 8) = l1v;
        // x part -> k 128..255
        const float4* xr = (const float4*)(xg + (size_t)n * FIN + ch * 16);
        float4 x0 = xr[0], x1 = xr[1], x2 = xr[2], x3 = xr[3];
        float xv[16] = {x0.x,x0.y,x0.z,x0.w, x1.x,x1.y,x1.z,x1.w,
                        x2.x,x2.y,x2.z,x2.w, x3.x,x3.y,x3.z,x3.w};
#pragma unroll
        for (int i = 0; i < 8; ++i) {
            __bf16 hb = (__bf16)xv[i];
            h0[i] = hb; l0[i] = (__bf16)(xv[i] - (float)hb);
            __bf16 hb2 = (__bf16)xv[i+8];
            h1v[i] = hb2; l1v[i] = (__bf16)(xv[i+8] - (float)hb2);
        }
        dh = &AH[lr * 264 + 128 + ch * 16];
        dl = &AL[lr * 264 + 128 + ch * 16];
        *(v8bf*)dh = h0; *(v8bf*)(dh + 8) = h1v;
        *(v8bf*)dl = l0; *(v8bf*)(dl + 8) = l1v;
    }
    __syncthreads();

    // phase B: 8 waves, wave w -> nt {2w,2w+1}, mt 0..3 (B reused 4x)
    int w = tid >> 6, lane = tid & 63, quad = lane >> 4, lm = lane & 15;
    v4f acc[4][2];
#pragma unroll
    for (int m = 0; m < 4; ++m) { acc[m][0] = (v4f)0.f; acc[m][1] = (v4f)0.f; }
    const v8bf* wpH = (const v8bf*)pH;
    const v8bf* wpL = (const v8bf*)pL;
    for (int kc = 0; kc < 8; ++kc) {
        v8bf bH0 = wpH[(kc * 16 + 2 * w    ) * 64 + lane];
        v8bf bL0 = wpL[(kc * 16 + 2 * w    ) * 64 + lane];
        v8bf bH1 = wpH[(kc * 16 + 2 * w + 1) * 64 + lane];
        v8bf bL1 = wpL[(kc * 16 + 2 * w + 1) * 64 + lane];
#pragma unroll
        for (int mt = 0; mt < 4; ++mt) {
            int ao = (mt * 16 + lm) * 264 + kc * 32 + quad * 8;
            v8bf aH = *(const v8bf*)&AH[ao];
            v8bf aL = *(const v8bf*)&AL[ao];
            acc[mt][0] = __builtin_amdgcn_mfma_f32_16x16x32_bf16(aH, bH0, acc[mt][0], 0, 0, 0);
            acc[mt][0] = __builtin_amdgcn_mfma_f32_16x16x32_bf16(aL, bH0, acc[mt][0], 0, 0, 0);
            acc[mt][0] = __builtin_amdgcn_mfma_f32_16x16x32_bf16(aH, bL0, acc[mt][0], 0, 0, 0);
            acc[mt][1] = __builtin_amdgcn_mfma_f32_16x16x32_bf16(aH, bH1, acc[mt][1], 0, 0, 0);
            acc[mt][1] = __builtin_amdgcn_mfma_f32_16x16x32_bf16(aL, bH1, acc[mt][1], 0, 0, 0);
            acc[mt][1] = __builtin_amdgcn_mfma_f32_16x16x32_bf16(aH, bL1, acc[mt][1], 0, 0, 0);
        }
    }
    // epilogue: bias+relu; u (cw-weighted) / v col sums over 64 rows. C/D: col=lane&15,row=quad*4+r
#pragma unroll
    for (int j = 0; j < 2; ++j) {
        int col = (2 * w + j) * 16 + lm;
        float bcol = bias[col];
        float su = 0.f, sv = 0.f;
#pragma unroll
        for (int mt = 0; mt < 4; ++mt) {
            int nb = g * Nc + r0 + mt * 16 + quad * 4;
#pragma unroll
            for (int r = 0; r < 4; ++r) {
                float val = fmaxf(acc[mt][j][r] + bcol, 0.f);
                sv += val;
                su += cw[nb + r] * val;
            }
        }
        su += __shfl_xor(su, 16); sv += __shfl_xor(sv, 16);
        su += __shfl_xor(su, 32); sv += __shfl_xor(sv, 32);
        if (quad == 0) {
            atomicAdd(&uv[g * 512 + col], su);
            atomicAdd(&uv[g * 512 + 256 + col], sv);
        }
    }
}

// ================= mega transformer: 1 block per batch, all stages in LDS =================
// gemm16: [16 x N] = A[16 x K] @ W[K x N], A fp32 in LDS (stride As), W fp32 global,
// hi/lo bf16 MFMA split. 16 waves; wave w covers nt = w, w+16, ...
__device__ __forceinline__ void gemm16(
        const float* __restrict__ A, int As,
        const float* __restrict__ W, int N, int K,
        const float* __restrict__ bias,
        float* __restrict__ O, int Os, int relu, int accum, int tid) {
    int w = tid >> 6, lane = tid & 63, quad = lane >> 4, lm = lane & 15;
    int ntot = N >> 4, kcs = K >> 5;
    for (int nt = w; nt < ntot; nt += 16) {
        v4f acc = (v4f)0.f;
        for (int kc = 0; kc < kcs; ++kc) {
            const float* ap = A + lm * As + kc * 32 + quad * 8;
            float4 f0 = *(const float4*)ap;
            float4 f1 = *(const float4*)(ap + 4);
            float av[8] = {f0.x, f0.y, f0.z, f0.w, f1.x, f1.y, f1.z, f1.w};
            v8bf aH, aL, bH, bL;
            const float* wp = W + (size_t)(kc * 32 + quad * 8) * N + nt * 16 + lm;
#pragma unroll
            for (int j = 0; j < 8; ++j) {
                __bf16 ah = (__bf16)av[j];
                aH[j] = ah; aL[j] = (__bf16)(av[j] - (float)ah);
                float wv = wp[(size_t)j * N];
                __bf16 wh = (__bf16)wv;
                bH[j] = wh; bL[j] = (__bf16)(wv - (float)wh);
            }
            acc = __builtin_amdgcn_mfma_f32_16x16x32_bf16(aH, bH, acc, 0, 0, 0);
            acc = __builtin_amdgcn_mfma_f32_16x16x32_bf16(aL, bH, acc, 0, 0, 0);
            acc = __builtin_amdgcn_mfma_f32_16x16x32_bf16(aH, bL, acc, 0, 0, 0);
        }
        int col = nt * 16 + lm;
        float bv = bias ? bias[col] : 0.f;
#pragma unroll
        for (int r = 0; r < 4; ++r) {
            int tok = quad * 4 + r;
            float val = acc[r] + bv;
            if (relu) val = fmaxf(val, 0.f);
            if (accum) O[tok * Os + col] += val;
            else       O[tok * Os + col] = val;
        }
    }
}

// per-token layernorm: wave w handles token w; out = LN(pre+res)*s + b
__device__ __forceinline__ void ln16(const float* __restrict__ pre, const float* __restrict__ res,
                                     const float* __restrict__ sc_, const float* __restrict__ bi,
                                     float* __restrict__ out, int tid) {
    int w = tid >> 6, lane = tid & 63;
    float4 pv = *(const float4*)&pre[w * 260 + lane * 4];
    float4 rv = *(const float4*)&res[w * 260 + lane * 4];
    float x0 = pv.x + rv.x, x1 = pv.y + rv.y, x2 = pv.z + rv.z, x3 = pv.w + rv.w;
    float s = x0 + x1 + x2 + x3;
    float q = x0*x0 + x1*x1 + x2*x2 + x3*x3;
#pragma unroll
    for (int o = 1; o < 64; o <<= 1) { s += __shfl_xor(s, o); q += __shfl_xor(q, o); }
    float m = s * (1.0f / 256.0f);
    float var = q * (1.0f / 256.0f) - m * m;
    float rstd = rsqrtf(var + EPSc);
    float4 sv = *(const float4*)&sc_[lane * 4];
    float4 bv = *(const float4*)&bi[lane * 4];
    float4 ov;
    ov.x = (x0 - m) * rstd * sv.x + bv.x;
    ov.y = (x1 - m) * rstd * sv.y + bv.y;
    ov.z = (x2 - m) * rstd * sv.z + bv.z;
    ov.w = (x3 - m) * rstd * sv.w + bv.w;
    *(float4*)&out[w * 260 + lane * 4] = ov;
}

__global__ __launch_bounds__(1024) void mega_kernel(
        const float* __restrict__ uv,
        const float* __restrict__ Wl2, const float* __restrict__ bl2, const float* __restrict__ Wr2,
        const float* __restrict__ Wqkv, const float* __restrict__ bqkv,
        const float* __restrict__ Wo, const float* __restrict__ bo,
        const float* __restrict__ ln1s, const float* __restrict__ ln1b,
        const float* __restrict__ W1, const float* __restrict__ b1,
        const float* __restrict__ W2, const float* __restrict__ b2,
        const float* __restrict__ ln2s, const float* __restrict__ ln2b,
        const float* __restrict__ fcW, const float* __restrict__ fcb,
        float* __restrict__ out) {
    __shared__ float h[16 * 260];
    __shared__ float big[16 * 1028];   // uvL (stride 516) -> qkv (772) -> ffn act (1028)
    __shared__ float ctx[16 * 260];
    __shared__ float pre[16 * 260];
    __shared__ float h1[16 * 260];
    __shared__ float sc[2048];         // [hd][qt][kt]
    int b = blockIdx.x, tid = threadIdx.x;

    // emb: load uv/1024 -> big [tok][516]; h = u@Wl2 + bl2 + v@Wr2
    for (int i = tid; i < 16 * 512; i += 1024) {
        int tok = i >> 9, k = i & 511;
        big[tok * 516 + k] = uv[(size_t)(b * 16 + tok) * 512 + k] * (1.0f / 1024.0f);
    }
    __syncthreads();
    gemm16(big,       516, Wl2, 256, 256, bl2,     h, 260, 0, 0, tid);
    __syncthreads();
    gemm16(big + 256, 516, Wr2, 256, 256, nullptr, h, 260, 0, 1, tid);
    __syncthreads();

    for (int l = 0; l < Lc; ++l) {
        // qkv -> big [tok][772]
        gemm16(h, 260, Wqkv + (size_t)l * Hc * 768, 768, 256, bqkv + l * 768, big, 772, 0, 0, tid);
        __syncthreads();
        // attention scores
#pragma unroll
        for (int rep = 0; rep < 2; ++rep) {
            int idx = rep * 1024 + tid;
            int hd = idx >> 8, qt = (idx >> 4) & 15, kt = idx & 15;
            float s = 0.f;
#pragma unroll
            for (int d = 0; d < 32; ++d)
                s += big[qt * 772 + hd * 32 + d] * big[kt * 772 + 256 + hd * 32 + d];
            sc[idx] = s * 0.17677669529663687f;
        }
        __syncthreads();
        if (tid < 128) {
            int base = tid * 16;
            float m = sc[base];
            for (int j = 1; j < 16; ++j) m = fmaxf(m, sc[base + j]);
            float ev[16], sum = 0.f;
            for (int j = 0; j < 16; ++j) { ev[j] = expf(sc[base + j] - m); sum += ev[j]; }
            float inv = 1.0f / sum;
            for (int j = 0; j < 16; ++j) sc[base + j] = ev[j] * inv;
        }
        __syncthreads();
#pragma unroll
        for (int rep = 0; rep < 4; ++rep) {
            int idx = rep * 1024 + tid;
            int qt = idx >> 8, c = idx & 255;
            int hd = c >> 5, d = c & 31;
            float o = 0.f;
#pragma unroll
            for (int j = 0; j < 16; ++j)
                o += sc[hd * 256 + qt * 16 + j] * big[j * 772 + 512 + hd * 32 + d];
            ctx[qt * 260 + c] = o;
        }
        __syncthreads();
        // proj -> pre; ln1 -> h1
        gemm16(ctx, 260, Wo + (size_t)l * 65536, 256, 256, bo + l * 256, pre, 260, 0, 0, tid);
        __syncthreads();
        ln16(pre, h, ln1s + l * 256, ln1b + l * 256, h1, tid);
        __syncthreads();
        // ffn1 -> big [tok][1028] (relu)
        gemm16(h1, 260, W1 + (size_t)l * 262144, 1024, 256, b1 + l * 1024, big, 1028, 1, 0, tid);
        __syncthreads();
        // ffn2 -> pre; ln2 -> h
        gemm16(big, 1028, W2 + (size_t)l * 262144, 256, 1024, b2 + l * 256, pre, 260, 0, 0, tid);
        __syncthreads();
        ln16(pre, h1, ln2s + l * 256, ln2b + l * 256, h, tid);
        __syncthreads();
    }
    // fc on token 15
    if (tid < 10) {
        float v = fcb[tid];
        for (int k = 0; k < 256; ++k) v += h[15 * 260 + k] * fcW[(size_t)k * 10 + tid];
        out[b * 10 + tid] = v;
    }
}

extern "C" void kernel_launch(void* const* d_in, const int* in_sizes, int n_in,
                              void* d_out, int out_size, void* d_ws, size_t ws_size,
                              hipStream_t stream) {
    (void)in_sizes; (void)n_in; (void)out_size; (void)ws_size;
    const float* x    = (const float*)d_in[0];
    const int*   ei   = (const int*)d_in[1];
    const float* s1Wl = (const float*)d_in[2];
    const float* s1bl = (const float*)d_in[3];
    const float* s1Wr = (const float*)d_in[4];
    const float* s2Wl = (const float*)d_in[5];
    const float* s2bl = (const float*)d_in[6];
    const float* s2Wr = (const float*)d_in[7];
    const float* Wqkv = (const float*)d_in[8];
    const float* bqkv = (const float*)d_in[9];
    const float* Wo   = (const float*)d_in[10];
    const float* bo   = (const float*)d_in[11];
    const float* ln1s = (const float*)d_in[12];
    const float* ln1b = (const float*)d_in[13];
    const float* W1   = (const float*)d_in[14];
    const float* b1   = (const float*)d_in[15];
    const float* W2   = (const float*)d_in[16];
    const float* b2   = (const float*)d_in[17];
    const float* ln2s = (const float*)d_in[18];
    const float* ln2b = (const float*)d_in[19];
    const float* fcW  = (const float*)d_in[20];
    const float* fcb  = (const float*)d_in[21];

    // workspace layout (total ~3.13 MB)
    char* ws = (char*)d_ws;
    __bf16*         pH     = (__bf16*)(ws + 0);          // 131072
    __bf16*         pL     = (__bf16*)(ws + 131072);     // 131072
    float*          invdeg = (float*)(ws + 262144);      // 262144
    float*          cw     = (float*)(ws + 524288);      // 262144
    int*            off    = (int*)(ws + 786432);        // 264192
    unsigned short* elist  = (unsigned short*)(ws + 1050624); // 2097152
    float*          uv     = (float*)(ws + 3147776);     // 131072 -> end 3278848

    prep_kernel<<<128, 1024, 0, stream>>>(ei, s1Wl, s1Wr, invdeg, cw, off, elist, uv, pH, pL);
    sage_kernel<<<Gc * 16, 512, 0, stream>>>(x, elist, off, invdeg, cw, pH, pL, s1bl, uv);
    mega_kernel<<<Bc, 1024, 0, stream>>>(uv, s2Wl, s2bl, s2Wr, Wqkv, bqkv, Wo, bo,
                                         ln1s, ln1b, W1, b1, W2, b2, ln2s, ln2b,
                                         fcW, fcb, (float*)d_out);
}

// Round 11
// 341.027 us; speedup vs baseline: 1.0430x; 1.0430x over previous
//
#include <hip/hip_runtime.h>
#include <hip/hip_bf16.h>

#define Bc 4
#define Tc 16
#define Nc 1024
#define Ec 16384
#define FIN 128
#define Hc 256
#define FFc 1024
#define NHc 8
#define Lc 2
#define HDc 32
#define Gc 64
#define EPSc 1e-5f
#define TPACK 1703936

typedef __bf16 v8bf __attribute__((ext_vector_type(8)));
typedef __bf16 v4bf __attribute__((ext_vector_type(4)));
typedef float v4f __attribute__((ext_vector_type(4)));

// ================= prep: 0-63 CSR, 64-127 sage W pack, 128-383 transformer W pack =================
__global__ __launch_bounds__(1024) void prep_kernel(
        const int* __restrict__ ei,
        const float* __restrict__ Wl, const float* __restrict__ Wr,
        const float* __restrict__ Wl2, const float* __restrict__ Wr2,
        const float* __restrict__ Wqkv, const float* __restrict__ Wo,
        const float* __restrict__ W1, const float* __restrict__ W2,
        float* __restrict__ invdeg, float* __restrict__ cw, int* __restrict__ off,
        unsigned short* __restrict__ elist, float* __restrict__ uv,
        __bf16* __restrict__ sgH, __bf16* __restrict__ sgL,
        __bf16* __restrict__ PT, int* __restrict__ bars) {
    __shared__ int degs[Nc];
    __shared__ float inv[Nc];
    __shared__ float cl[Nc];
    __shared__ int wsum[16];
    int t = threadIdx.x;
    if (blockIdx.x >= 128) {
        // transformer pack: MFMA B-frag order, bf16 hi at PT[idx], lo at PT[TPACK+idx]
        size_t base = (size_t)(blockIdx.x - 128) * 1024 + t;
        for (size_t idx = base; idx < TPACK; idx += 262144) {
            size_t local; int NT, N; const float* src;
            if (idx < 131072)       { local = idx;           NT = 16; N = 256;  src = nullptr; }
            else if (idx < 327680)  { local = idx - 131072;  NT = 48; N = 768;  src = Wqkv; }
            else if (idx < 524288)  { local = idx - 327680;  NT = 48; N = 768;  src = Wqkv + 196608; }
            else if (idx < 589824)  { local = idx - 524288;  NT = 16; N = 256;  src = Wo; }
            else if (idx < 655360)  { local = idx - 589824;  NT = 16; N = 256;  src = Wo + 65536; }
            else if (idx < 917504)  { local = idx - 655360;  NT = 64; N = 1024; src = W1; }
            else if (idx < 1179648) { local = idx - 917504;  NT = 64; N = 1024; src = W1 + 262144; }
            else if (idx < 1441792) { local = idx - 1179648; NT = 16; N = 256;  src = W2; }
            else                    { local = idx - 1441792; NT = 16; N = 256;  src = W2 + 262144; }
            int j = local & 7, lane = (local >> 3) & 63;
            int t2 = (int)(local >> 9);
            int nt = t2 % NT, kc = t2 / NT;
            int k = kc * 32 + ((lane >> 4) << 3) + j;
            int n = nt * 16 + (lane & 15);
            float v;
            if (src) v = src[(size_t)k * N + n];
            else v = (k < 256) ? Wl2[(size_t)k * 256 + n] : Wr2[(size_t)(k - 256) * 256 + n];
            __bf16 hi = (__bf16)v;
            PT[idx] = hi;
            PT[TPACK + idx] = (__bf16)(v - (float)hi);
        }
        return;
    }
    if (blockIdx.x >= 64) {
        // sage pack: Wcat[256][256]=[Wl;Wr] -> B-frag, hi+lo
        int id = (blockIdx.x - 64) * 1024 + t;       // 0..65535
        int tt = id & 511, bidOld = id >> 9;
        int lane = tt >> 3, j = tt & 7;
        int kc = bidOld >> 4, nt = bidOld & 15;
        int k = kc * 32 + ((lane >> 4) << 3) + j;
        int n = nt * 16 + (lane & 15);
        float wv = (k < 128) ? Wl[(size_t)k * Hc + n] : Wr[(size_t)(k - 128) * Hc + n];
        __bf16 hi = (__bf16)wv;
        sgH[id] = hi;
        sgL[id] = (__bf16)(wv - (float)hi);
        return;
    }
    int g = blockIdx.x;
    if (g == 0 && t < 16) bars[t] = 0;
    const int* src = ei + (size_t)g * 2 * Ec;
    const int* dst = src + Ec;
    if (t < 512) uv[g * 512 + t] = 0.f;
    degs[t] = 0; cl[t] = 0.f;
    __syncthreads();
    for (int e = t; e < Ec; e += 1024) atomicAdd(&degs[dst[e] & (Nc - 1)], 1);
    __syncthreads();
    float iv = 1.0f / fmaxf((float)degs[t], 1.0f);
    inv[t] = iv;
    invdeg[g * Nc + t] = iv;
    __syncthreads();
    for (int e = t; e < Ec; e += 1024) atomicAdd(&cl[src[e] & (Nc - 1)], inv[dst[e] & (Nc - 1)]);
    __syncthreads();
    cw[g * Nc + t] = cl[t];
    int own = degs[t];
    int lane = t & 63, wv2 = t >> 6;
    int val = own;
#pragma unroll
    for (int ofs = 1; ofs < 64; ofs <<= 1) {
        int v = __shfl_up(val, ofs, 64);
        if (lane >= ofs) val += v;
    }
    if (lane == 63) wsum[wv2] = val;
    __syncthreads();
    if (wv2 == 0 && lane < 16) {
        int wval = wsum[lane];
#pragma unroll
        for (int ofs = 1; ofs < 16; ofs <<= 1) {
            int v = __shfl_up(wval, ofs, 64);
            if (lane >= ofs) wval += v;
        }
        wsum[lane] = wval;
    }
    __syncthreads();
    int incl = val + ((wv2 > 0) ? wsum[wv2 - 1] : 0);
    int excl = incl - own;
    off[g * 1032 + t] = excl;
    if (t == 1023) off[g * 1032 + Nc] = incl;
    degs[t] = excl;
    __syncthreads();
    for (int e = t; e < Ec; e += 1024) {
        int d = dst[e] & (Nc - 1);
        int slot = atomicAdd(&degs[d], 1);
        elist[(size_t)g * Ec + slot] = (unsigned short)(src[e] & (Nc - 1));
    }
}

// ================= SAGE v4: 64-row blocks, A bf16-hi LDS, W hi/lo, 2 MFMA =================
__global__ __launch_bounds__(512, 8) void sage_kernel(
        const float* __restrict__ x, const unsigned short* __restrict__ elist,
        const int* __restrict__ off, const float* __restrict__ invdeg,
        const float* __restrict__ cw, const __bf16* __restrict__ sgH,
        const __bf16* __restrict__ sgL, const float* __restrict__ bias,
        float* __restrict__ uv) {
    __shared__ __bf16 AH[64 * 264];    // 33792 B
    int tid = threadIdx.x, bid = blockIdx.x;
    int g = bid & 63, cc = bid >> 6, r0 = cc * 64;   // XCD swizzle: graph -> one XCD
    const unsigned short* el = elist + (size_t)g * Ec;
    const float* xg = x + (size_t)g * Nc * FIN;

    // phase A: 1024 items (row lr, 8-float chunk ch), 2 per thread
    for (int it = tid; it < 1024; it += 512) {
        int lr = it >> 4, ch = it & 15;
        int n = r0 + lr;
        int o0 = off[g * 1032 + n], o1 = off[g * 1032 + n + 1];
        float4 a0 = {0.f, 0.f, 0.f, 0.f}, a1 = a0;
        const float* xc = xg + ch * 8;
        int e = o0;
        for (; e + 4 <= o1; e += 4) {
            int s0 = el[e], s1 = el[e + 1], s2 = el[e + 2], s3 = el[e + 3];
            const float4* p0 = (const float4*)(xc + (size_t)s0 * FIN);
            const float4* p1 = (const float4*)(xc + (size_t)s1 * FIN);
            const float4* p2 = (const float4*)(xc + (size_t)s2 * FIN);
            const float4* p3 = (const float4*)(xc + (size_t)s3 * FIN);
            float4 u0 = p0[0], v0 = p0[1], u1 = p1[0], v1 = p1[1];
            float4 u2 = p2[0], v2 = p2[1], u3 = p3[0], v3 = p3[1];
            a0.x += u0.x + u1.x + u2.x + u3.x; a0.y += u0.y + u1.y + u2.y + u3.y;
            a0.z += u0.z + u1.z + u2.z + u3.z; a0.w += u0.w + u1.w + u2.w + u3.w;
            a1.x += v0.x + v1.x + v2.x + v3.x; a1.y += v0.y + v1.y + v2.y + v3.y;
            a1.z += v0.z + v1.z + v2.z + v3.z; a1.w += v0.w + v1.w + v2.w + v3.w;
        }
        for (; e < o1; ++e) {
            const float4* p = (const float4*)(xc + (size_t)el[e] * FIN);
            float4 u0 = p[0], v0 = p[1];
            a0.x += u0.x; a0.y += u0.y; a0.z += u0.z; a0.w += u0.w;
            a1.x += v0.x; a1.y += v0.y; a1.z += v0.z; a1.w += v0.w;
        }
        float iv = invdeg[g * Nc + n];
        v8bf oa;
        oa[0] = (__bf16)(a0.x * iv); oa[1] = (__bf16)(a0.y * iv);
        oa[2] = (__bf16)(a0.z * iv); oa[3] = (__bf16)(a0.w * iv);
        oa[4] = (__bf16)(a1.x * iv); oa[5] = (__bf16)(a1.y * iv);
        oa[6] = (__bf16)(a1.z * iv); oa[7] = (__bf16)(a1.w * iv);
        *(v8bf*)&AH[lr * 264 + ch * 8] = oa;
        const float4* xr = (const float4*)(xg + (size_t)n * FIN + ch * 8);
        float4 x0 = xr[0], x1 = xr[1];
        v8bf ox;
        ox[0] = (__bf16)x0.x; ox[1] = (__bf16)x0.y; ox[2] = (__bf16)x0.z; ox[3] = (__bf16)x0.w;
        ox[4] = (__bf16)x1.x; ox[5] = (__bf16)x1.y; ox[6] = (__bf16)x1.z; ox[7] = (__bf16)x1.w;
        *(v8bf*)&AH[lr * 264 + 128 + ch * 8] = ox;
    }
    __syncthreads();

    // phase B: 8 waves, wave w -> nt {2w,2w+1}, mt 0..3
    int w = tid >> 6, lane = tid & 63, quad = lane >> 4, lm = lane & 15;
    v4f acc[4][2];
#pragma unroll
    for (int m = 0; m < 4; ++m) { acc[m][0] = (v4f)0.f; acc[m][1] = (v4f)0.f; }
    const v8bf* wpH = (const v8bf*)sgH;
    const v8bf* wpL = (const v8bf*)sgL;
    for (int kc = 0; kc < 8; ++kc) {
        v8bf bH0 = wpH[(kc * 16 + 2 * w    ) * 64 + lane];
        v8bf bL0 = wpL[(kc * 16 + 2 * w    ) * 64 + lane];
        v8bf bH1 = wpH[(kc * 16 + 2 * w + 1) * 64 + lane];
        v8bf bL1 = wpL[(kc * 16 + 2 * w + 1) * 64 + lane];
#pragma unroll
        for (int mt = 0; mt < 4; ++mt) {
            v8bf aH = *(const v8bf*)&AH[(mt * 16 + lm) * 264 + kc * 32 + quad * 8];
            acc[mt][0] = __builtin_amdgcn_mfma_f32_16x16x32_bf16(aH, bH0, acc[mt][0], 0, 0, 0);
            acc[mt][0] = __builtin_amdgcn_mfma_f32_16x16x32_bf16(aH, bL0, acc[mt][0], 0, 0, 0);
            acc[mt][1] = __builtin_amdgcn_mfma_f32_16x16x32_bf16(aH, bH1, acc[mt][1], 0, 0, 0);
            acc[mt][1] = __builtin_amdgcn_mfma_f32_16x16x32_bf16(aH, bL1, acc[mt][1], 0, 0, 0);
        }
    }
    // epilogue: C/D col=lane&15, row=quad*4+r
#pragma unroll
    for (int j = 0; j < 2; ++j) {
        int col = (2 * w + j) * 16 + lm;
        float bcol = bias[col];
        float su = 0.f, sv = 0.f;
#pragma unroll
        for (int mt = 0; mt < 4; ++mt) {
            int nb = g * Nc + r0 + mt * 16 + quad * 4;
#pragma unroll
            for (int r = 0; r < 4; ++r) {
                float val = fmaxf(acc[mt][j][r] + bcol, 0.f);
                sv += val;
                su += cw[nb + r] * val;
            }
        }
        su += __shfl_xor(su, 16); sv += __shfl_xor(sv, 16);
        su += __shfl_xor(su, 32); sv += __shfl_xor(sv, 32);
        if (quad == 0) {
            atomicAdd(&uv[g * 512 + col], su);
            atomicAdd(&uv[g * 512 + 256 + col], sv);
        }
    }
}

// ================= transformer: 64 blocks (16 per batch), batch-local barriers =================
__device__ __forceinline__ void gbar(int* cnt, int* gen, int nb) {
    __syncthreads();
    if (threadIdx.x == 0) {
        __threadfence();
        int g = __hip_atomic_load(gen, __ATOMIC_RELAXED, __HIP_MEMORY_SCOPE_AGENT);
        int prev = __hip_atomic_fetch_add(cnt, 1, __ATOMIC_ACQ_REL, __HIP_MEMORY_SCOPE_AGENT);
        if (prev == nb - 1) {
            __hip_atomic_store(cnt, 0, __ATOMIC_RELAXED, __HIP_MEMORY_SCOPE_AGENT);
            __hip_atomic_fetch_add(gen, 1, __ATOMIC_RELEASE, __HIP_MEMORY_SCOPE_AGENT);
        } else {
            while (__hip_atomic_load(gen, __ATOMIC_ACQUIRE, __HIP_MEMORY_SCOPE_AGENT) == g)
                __builtin_amdgcn_s_sleep(4);
        }
        __threadfence();
    }
    __syncthreads();
}

__device__ __forceinline__ v4f mfma_nt(const __bf16* AH, int As, const __bf16* PT,
                                       int segOff, int NT, int nt, int kcs, int lane) {
    int quad = lane >> 4, lm = lane & 15;
    v4f acc = (v4f)0.f;
    const __bf16* BH = PT + segOff;
    const __bf16* BL = PT + TPACK + segOff;
    for (int kc = 0; kc < kcs; ++kc) {
        v8bf a = *(const v8bf*)(AH + lm * As + kc * 32 + quad * 8);
        size_t bo_ = ((size_t)(kc * NT + nt) * 64 + lane) * 8;
        v8bf bH = *(const v8bf*)(BH + bo_);
        v8bf bL = *(const v8bf*)(BL + bo_);
        acc = __builtin_amdgcn_mfma_f32_16x16x32_bf16(a, bH, acc, 0, 0, 0);
        acc = __builtin_amdgcn_mfma_f32_16x16x32_bf16(a, bL, acc, 0, 0, 0);
    }
    return acc;
}

__device__ __forceinline__ void stage_AH(const float* src, int g0, int K, int srcStride,
                                         float scale, __bf16* AH, int As, int tid) {
    int Kq = K >> 2;
    for (int i = tid; i < 16 * Kq; i += 256) {
        int row = i / Kq, c = i - row * Kq;
        float4 v = *(const float4*)(src + (size_t)(g0 + row) * srcStride + c * 4);
        v4bf o;
        o[0] = (__bf16)(v.x * scale); o[1] = (__bf16)(v.y * scale);
        o[2] = (__bf16)(v.z * scale); o[3] = (__bf16)(v.w * scale);
        *(v4bf*)(AH + row * As + c * 4) = o;
    }
}

__device__ __forceinline__ void ln_stage(const float* src, int g0, const float* s,
                                         const float* bln, __bf16* AH, float* hout, int tid) {
    int w = tid >> 6, lane = tid & 63;
    for (int t = w; t < 16; t += 4) {
        const float* row = src + (size_t)(g0 + t) * 256;
        float4 v = *(const float4*)(row + lane * 4);
        float sm = v.x + v.y + v.z + v.w;
        float sq = v.x * v.x + v.y * v.y + v.z * v.z + v.w * v.w;
#pragma unroll
        for (int o = 1; o < 64; o <<= 1) { sm += __shfl_xor(sm, o); sq += __shfl_xor(sq, o); }
        float m = sm * (1.0f / 256.0f);
        float var = sq * (1.0f / 256.0f) - m * m;
        float rs = rsqrtf(var + EPSc);
        float4 sv = *(const float4*)(s + lane * 4);
        float4 bv = *(const float4*)(bln + lane * 4);
        float o0 = (v.x - m) * rs * sv.x + bv.x, o1 = (v.y - m) * rs * sv.y + bv.y;
        float o2 = (v.z - m) * rs * sv.z + bv.z, o3 = (v.w - m) * rs * sv.w + bv.w;
        v4bf ob;
        ob[0] = (__bf16)o0; ob[1] = (__bf16)o1; ob[2] = (__bf16)o2; ob[3] = (__bf16)o3;
        *(v4bf*)(AH + t * 264 + lane * 4) = ob;
        if (hout) {
            float4 ov = {o0, o1, o2, o3};
            *(float4*)(hout + (size_t)(g0 + t) * 256 + lane * 4) = ov;
        }
    }
}

__global__ __launch_bounds__(256) void xform_kernel(
        const float* __restrict__ uv, const __bf16* __restrict__ PT,
        const float* __restrict__ bl2, const float* __restrict__ bqkv,
        const float* __restrict__ bo, const float* __restrict__ ln1s,
        const float* __restrict__ ln1b, const float* __restrict__ b1f,
        const float* __restrict__ b2f, const float* __restrict__ ln2s,
        const float* __restrict__ ln2b, const float* __restrict__ fcW,
        const float* __restrict__ fcb,
        float* __restrict__ h, float* __restrict__ qkvg, float* __restrict__ h1,
        float* __restrict__ pre2, float* __restrict__ f,
        int* __restrict__ bars, float* __restrict__ out) {
    __shared__ __align__(16) char smem[66560];
    int tid = threadIdx.x;
    int b = blockIdx.x >> 4, sb = blockIdx.x & 15;
    int w = tid >> 6, lane = tid & 63, quad = lane >> 4, lm = lane & 15;
    int* cnt = bars + b;
    int* gen = bars + 8 + b;
    int g0 = b * 16;
    __bf16* AH = (__bf16*)smem;

    // ---- E: h = [u|v]/N @ [Wl2;Wr2] + bl2 ----
    stage_AH(uv, g0, 512, 512, 1.0f / 1024.0f, AH, 520, tid);
    __syncthreads();
    if (w == 0) {
        v4f acc = mfma_nt(AH, 520, PT, 0, 16, sb, 16, lane);
        int col = sb * 16 + lm;
#pragma unroll
        for (int r = 0; r < 4; ++r)
            h[(size_t)(g0 + quad * 4 + r) * 256 + col] = acc[r] + bl2[col];
    }
    gbar(cnt, gen, 16);

    for (int l = 0; l < Lc; ++l) {
        // ---- Q: qkv = h @ Wqkv + b (h = ln2(pre2) on-stage for l>=1) ----
        if (l == 0) stage_AH(h, g0, 256, 256, 1.0f, AH, 264, tid);
        else ln_stage(pre2, g0, ln2s + (l - 1) * 256, ln2b + (l - 1) * 256, AH,
                      (sb == 0) ? h : nullptr, tid);
        __syncthreads();
        if (w < 3) {
            int nt = sb * 3 + w;
            v4f acc = mfma_nt(AH, 264, PT, 131072 + l * 196608, 48, nt, 8, lane);
            int col = nt * 16 + lm;
#pragma unroll
            for (int r = 0; r < 4; ++r)
                qkvg[(size_t)(g0 + quad * 4 + r) * 768 + col] = acc[r] + bqkv[l * 768 + col];
        }
        gbar(cnt, gen, 16);
        // ---- A: attention + proj -> pre2 = h + bo + ctx@Wo ----
        {
            float* qkvL = (float*)smem;                 // 16 x 772
            float* sc = (float*)(smem + 49408);         // 2048
            __bf16* cAH = (__bf16*)(smem + 57600);      // 16 x 264
            for (int i = tid; i < 3072; i += 256) {
                int row = i / 192, c = i - row * 192;
                *(float4*)&qkvL[row * 772 + c * 4] =
                    *(const float4*)&qkvg[(size_t)(g0 + row) * 768 + c * 4];
            }
            __syncthreads();
#pragma unroll
            for (int hd = 0; hd < 8; ++hd) {
                int qt = tid >> 4, kt = tid & 15;
                float s = 0.f;
#pragma unroll
                for (int d = 0; d < 32; ++d)
                    s += qkvL[qt * 772 + hd * 32 + d] * qkvL[kt * 772 + 256 + hd * 32 + d];
                sc[hd * 256 + qt * 16 + kt] = s * 0.17677669529663687f;
            }
            __syncthreads();
            if (tid < 128) {
                int base = tid * 16;
                float m = sc[base];
                for (int j = 1; j < 16; ++j) m = fmaxf(m, sc[base + j]);
                float ev[16], sum = 0.f;
                for (int j = 0; j < 16; ++j) { ev[j] = expf(sc[base + j] - m); sum += ev[j]; }
                float inv = 1.0f / sum;
                for (int j = 0; j < 16; ++j) sc[base + j] = ev[j] * inv;
            }
            __syncthreads();
            for (int i = tid; i < 4096; i += 256) {
                int qt = i >> 8, c = i & 255, hd = c >> 5, d = c & 31;
                float o = 0.f;
#pragma unroll
                for (int j = 0; j < 16; ++j)
                    o += sc[hd * 256 + qt * 16 + j] * qkvL[j * 772 + 512 + hd * 32 + d];
                cAH[qt * 264 + c] = (__bf16)o;
            }
            __syncthreads();
            if (w == 0) {
                v4f acc = mfma_nt(cAH, 264, PT, 524288 + l * 65536, 16, sb, 8, lane);
                int col = sb * 16 + lm;
#pragma unroll
                for (int r = 0; r < 4; ++r) {
                    int gg = g0 + quad * 4 + r;
                    pre2[(size_t)gg * 256 + col] =
                        h[(size_t)gg * 256 + col] + bo[l * 256 + col] + acc[r];
                }
            }
        }
        gbar(cnt, gen, 16);
        // ---- F1: f = relu(ln1(pre2) @ W1 + b1) ----
        ln_stage(pre2, g0, ln1s + l * 256, ln1b + l * 256, AH, (sb == 0) ? h1 : nullptr, tid);
        __syncthreads();
        {
            int nt = sb * 4 + w;
            v4f acc = mfma_nt(AH, 264, PT, 655360 + l * 262144, 64, nt, 8, lane);
            int col = nt * 16 + lm;
#pragma unroll
            for (int r = 0; r < 4; ++r)
                f[(size_t)(g0 + quad * 4 + r) * 1024 + col] =
                    fmaxf(acc[r] + b1f[l * 1024 + col], 0.f);
        }
        gbar(cnt, gen, 16);
        // ---- F2: pre2 = h1 + b2 + f @ W2 ----
        stage_AH(f, g0, 1024, 1024, 1.0f, AH, 1032, tid);
        __syncthreads();
        if (w == 0) {
            v4f acc = mfma_nt(AH, 1032, PT, 1179648 + l * 262144, 16, sb, 32, lane);
            int col = sb * 16 + lm;
#pragma unroll
            for (int r = 0; r < 4; ++r) {
                int gg = g0 + quad * 4 + r;
                pre2[(size_t)gg * 256 + col] =
                    h1[(size_t)gg * 256 + col] + b2f[l * 256 + col] + acc[r];
            }
        }
        gbar(cnt, gen, 16);
    }
    // ---- FC on token 15 of this batch ----
    if (sb == 0) {
        float* hrow = (float*)smem;
        float* mrs = (float*)(smem + 1088);
        int gg = g0 + 15;
        if (w == 0) {
            float4 v = *(const float4*)&pre2[(size_t)gg * 256 + lane * 4];
            float sm = v.x + v.y + v.z + v.w;
            float sq = v.x * v.x + v.y * v.y + v.z * v.z + v.w * v.w;
#pragma unroll
            for (int o = 1; o < 64; o <<= 1) { sm += __shfl_xor(sm, o); sq += __shfl_xor(sq, o); }
            if (lane == 0) {
                float m = sm * (1.0f / 256.0f);
                mrs[0] = m;
                mrs[1] = rsqrtf(sq * (1.0f / 256.0f) - m * m + EPSc);
            }
        }
        __syncthreads();
        float m = mrs[0], rs = mrs[1];
        hrow[tid] = (pre2[(size_t)gg * 256 + tid] - m) * rs * ln2s[256 + tid] + ln2b[256 + tid];
        __syncthreads();
        if (tid < 10) {
            float v = fcb[tid];
            for (int k = 0; k < 256; ++k) v += hrow[k] * fcW[(size_t)k * 10 + tid];
            out[b * 10 + tid] = v;
        }
    }
}

extern "C" void kernel_launch(void* const* d_in, const int* in_sizes, int n_in,
                              void* d_out, int out_size, void* d_ws, size_t ws_size,
                              hipStream_t stream) {
    (void)in_sizes; (void)n_in; (void)out_size; (void)ws_size;
    const float* x    = (const float*)d_in[0];
    const int*   ei   = (const int*)d_in[1];
    const float* s1Wl = (const float*)d_in[2];
    const float* s1bl = (const float*)d_in[3];
    const float* s1Wr = (const float*)d_in[4];
    const float* s2Wl = (const float*)d_in[5];
    const float* s2bl = (const float*)d_in[6];
    const float* s2Wr = (const float*)d_in[7];
    const float* Wqkv = (const float*)d_in[8];
    const float* bqkv = (const float*)d_in[9];
    const float* Wo   = (const float*)d_in[10];
    const float* bo   = (const float*)d_in[11];
    const float* ln1s = (const float*)d_in[12];
    const float* ln1b = (const float*)d_in[13];
    const float* W1   = (const float*)d_in[14];
    const float* b1   = (const float*)d_in[15];
    const float* W2   = (const float*)d_in[16];
    const float* b2   = (const float*)d_in[17];
    const float* ln2s = (const float*)d_in[18];
    const float* ln2b = (const float*)d_in[19];
    const float* fcW  = (const float*)d_in[20];
    const float* fcb  = (const float*)d_in[21];

    // workspace (~10.3 MB)
    char* ws = (char*)d_ws;
    __bf16*         PT     = (__bf16*)(ws + 0);               // 6,815,744
    __bf16*         sgH    = (__bf16*)(ws + 6815744);         // 131072
    __bf16*         sgL    = (__bf16*)(ws + 6946816);         // 131072
    float*          invdeg = (float*)(ws + 7077888);          // 262144
    float*          cw     = (float*)(ws + 7340032);          // 262144
    int*            off    = (int*)(ws + 7602176);            // 264192
    unsigned short* elist  = (unsigned short*)(ws + 7866368); // 2097152
    float*          uv     = (float*)(ws + 9963520);          // 131072
    float*          h      = (float*)(ws + 10094592);         // 65536
    float*          qkvg   = (float*)(ws + 10160128);         // 196608
    float*          h1     = (float*)(ws + 10356736);         // 65536
    float*          pre2   = (float*)(ws + 10422272);         // 65536
    float*          f      = (float*)(ws + 10487808);         // 262144
    int*            bars   = (int*)(ws + 10749952);           // 64

    prep_kernel<<<384, 1024, 0, stream>>>(ei, s1Wl, s1Wr, s2Wl, s2Wr, Wqkv, Wo, W1, W2,
                                          invdeg, cw, off, elist, uv, sgH, sgL, PT, bars);
    sage_kernel<<<Gc * 16, 512, 0, stream>>>(x, elist, off, invdeg, cw, sgH, sgL, s1bl, uv);
    xform_kernel<<<Gc, 256, 0, stream>>>(uv, PT, s2bl, bqkv, bo, ln1s, ln1b, b1, b2,
                                         ln2s, ln2b, fcW, fcb, h, qkvg, h1, pre2, f,
                                         bars, (float*)d_out);
}